// Round 6
// baseline (2341.766 us; speedup 1.0000x reference)
//
#include <hip/hip_runtime.h>

#define NV 200000
#define NDN 25000
#define EPSV 1e-5f

typedef short bf16x8 __attribute__((ext_vector_type(8)));
typedef float f32x16 __attribute__((ext_vector_type(16)));

static __device__ __forceinline__ float silu_f(float v) { return v / (1.0f + __expf(-v)); }
static __device__ __forceinline__ unsigned short f2b(float f) {
    unsigned u = __float_as_uint(f);
    return (unsigned short)((u + 0x7FFFu + ((u >> 16) & 1u)) >> 16);
}
static __device__ __forceinline__ float b2f(unsigned short h) {
    return __uint_as_float(((unsigned)h) << 16);
}
static __device__ __forceinline__ bf16x8 bc8(uint4 v) { return __builtin_bit_cast(bf16x8, v); }
#define MFMA32(a, b, c) __builtin_amdgcn_mfma_f32_32x32x16_bf16(a, b, c, 0, 0, 0)

// LDS unit index for (row r in [0,64), chunk c): bank-quad = (r+c)%8, balanced
// for BOTH coalesced writes (fixed r, c varies) and frag reads (fixed c, r varies).
#define U2(r, c) ((((r) >> 5) * 8 + ((c) >> 1)) * 64 + (((c) & 1) * 32) + ((((r) + (c)) & 7) | ((r) & 24)))
#define U1(r, c) ((((r) >> 5) * 4 + ((c) >> 1)) * 64 + (((c) & 1) * 32) + ((((r) + (c)) & 7) | ((r) & 24)))

// workspace byte offsets
#define OFF_STATS1 0                               // 128 f32
#define OFF_STATS2 512                             // 256 f32
#define OFF_TP     4096                            // 16*256 f32
#define OFF_W1B    32768                           // bf16 swizzled 27*64*128
#define OFF_W2B    (OFF_W1B + 27 * 64 * 128 * 2)   // 27*128*128
#define OFF_WDB    (OFF_W2B + 27 * 128 * 128 * 2)  // 8*128*128
#define OFF_WIDB   (OFF_WDB + 8 * 128 * 128 * 2)   // 64*128
#define OFF_H1     (2u << 20)                      // bf16 (NV+1)*64  (row NV = zeros)
#define OFF_H2     (28u << 20)                     // bf16 (NV+1)*128 (row NV = zeros; h2 then h3 in place)
#define OFF_H4     (80u << 20)                     // bf16 NV*128

// ---------------- small kernels ----------------

__global__ void k_init(float* stats, unsigned int* h1z, unsigned int* h2z) {
    int i = threadIdx.x;
    if (i < 384) stats[i] = 0.0f;
    else if (i < 416) h1z[i - 384] = 0u;   // H1 row NV
    else if (i < 480) h2z[i - 416] = 0u;   // H2 row NV
}

__global__ __launch_bounds__(256) void k_stats1(const float* __restrict__ x,
                                                float* __restrict__ stats) {
    int c = threadIdx.x & 63;
    int r0 = blockIdx.x * 4 + (threadIdx.x >> 6);
    float s = 0.f, q = 0.f;
    for (int r = r0; r < NV; r += gridDim.x * 4) {
        float v = x[r * 64 + c];
        s += v; q += v * v;
    }
    __shared__ float rs[256], rq[256];
    rs[threadIdx.x] = s; rq[threadIdx.x] = q;
    __syncthreads();
    if (threadIdx.x < 64) {
        s = rs[threadIdx.x] + rs[threadIdx.x + 64] + rs[threadIdx.x + 128] + rs[threadIdx.x + 192];
        q = rq[threadIdx.x] + rq[threadIdx.x + 64] + rq[threadIdx.x + 128] + rq[threadIdx.x + 192];
        atomicAdd(&stats[c], s);
        atomicAdd(&stats[64 + c], q);
    }
}

__global__ __launch_bounds__(256) void k_tp(const float* __restrict__ t,
                                            const float* __restrict__ Wt,
                                            const float* __restrict__ bt,
                                            float* __restrict__ tp) {
    __shared__ float st[256];
    int b = blockIdx.x, o = threadIdx.x;
    st[o] = silu_f(t[b * 256 + o]);
    __syncthreads();
    float acc = bt[o];
    for (int e = 0; e < 256; e++) acc += st[e] * Wt[e * 256 + o];
    tp[b * 256 + o] = acc;
}

// weights fp32 [K][CI][128] -> bf16 fragment-order units
__global__ __launch_bounds__(256) void k_swz(const float* __restrict__ W, uint4* __restrict__ dst,
                                             int Kc, int S) {
    int t = blockIdx.x * 256 + threadIdx.x;
    int total = Kc * S * 4 * 64;
    if (t >= total) return;
    int L = t & 63;
    int u = t >> 6;
    int nt = u & 3; u >>= 2;
    int s = u % S;
    int kk = u / S;
    int CI = S * 16;
    int c0 = s * 16 + (L >> 5) * 8;
    int f = nt * 32 + (L & 31);
    union { unsigned short e[8]; uint4 v; } uu;
#pragma unroll
    for (int j = 0; j < 8; j++) uu.e[j] = f2b(W[(kk * CI + c0 + j) * 128 + f]);
    dst[t] = uu.v;
}

__global__ __launch_bounds__(256) void k_h1(const float* __restrict__ x,
                                            const float* __restrict__ g1,
                                            const float* __restrict__ be1,
                                            const float* __restrict__ stats,
                                            unsigned short* __restrict__ H1) {
    int i = blockIdx.x * 256 + threadIdx.x;   // < NV*16
    if (i >= NV * 16) return;
    int c4 = (i & 15) * 4;
    float4 v = ((const float4*)x)[i];
    float vv[4] = {v.x, v.y, v.z, v.w};
    ushort4 o;
    unsigned short os[4];
#pragma unroll
    for (int j = 0; j < 4; j++) {
        int c = c4 + j;
        float m = stats[c] * (1.0f / NV);
        float var = stats[64 + c] * (1.0f / NV) - m * m;
        float a = g1[c] * rsqrtf(var + EPSV);
        float b = be1[c] - m * a;
        os[j] = f2b(silu_f(vv[j] * a + b));
    }
    o.x = os[0]; o.y = os[1]; o.z = os[2]; o.w = os[3];
    ((ushort4*)H1)[i] = o;
}

__global__ __launch_bounds__(256) void k_h3(unsigned short* __restrict__ H,
                                            const float* __restrict__ g2,
                                            const float* __restrict__ be2,
                                            const float* __restrict__ stats2) {
    int i = blockIdx.x * 256 + threadIdx.x;   // < NV*16 (uint4 of 8 bf16)
    if (i >= NV * 16) return;
    union { uint4 v; unsigned short e[8]; } uu;
    uu.v = ((const uint4*)H)[i];
    int f0 = (i & 15) * 8;
#pragma unroll
    for (int j = 0; j < 8; j++) {
        int f = f0 + j;
        float m = stats2[f] * (1.0f / NV);
        float var = stats2[128 + f] * (1.0f / NV) - m * m;
        float a = g2[f] * rsqrtf(var + EPSV);
        float b = be2[f] - m * a;
        uu.e[j] = f2b(silu_f(b2f(uu.e[j]) * a + b));
    }
    ((uint4*)H)[i] = uu.v;
}

// ---------------- conv kernels ----------------
// Coalesced gather -> VGPR -> wave-private LDS (swizzled, conflict-free) -> frag read.
// NO barriers in K-loop. Per-iter order: ds_write G(k) [one vmcnt(0) here, a full
// iteration after issue] -> issue gathers G(k+1) -> idx(k+2) -> ds_read+MFMA with
// pre-loaded B(k) (no vmem wait) -> load B(k+1).
// Missing neighbors (-1) -> reserved zero row NV.

__global__ __launch_bounds__(256, 2) void k_conv1(const unsigned short* __restrict__ H1,
                                                  const int* __restrict__ nbr,
                                                  const uint4* __restrict__ W1b,
                                                  const float* __restrict__ b1,
                                                  const int* __restrict__ b_idx,
                                                  const float* __restrict__ tp,
                                                  unsigned short* __restrict__ H2,
                                                  float* __restrict__ stats2) {
    __shared__ uint4 smA[2048];   // 4 waves x 512 units (8 KB/wave)
    __shared__ float ssum[128], ssq[128];
    int tid = threadIdx.x;
    int w = tid >> 6, lane = tid & 63, m = lane & 31, h = lane >> 5;
    int n0 = blockIdx.x * 128;
    int rt0 = (w >> 1) * 2, nt0 = (w & 1) * 2;
    int rbase = n0 + rt0 * 32;
    uint4* smW = &smA[w * 512];
    const uint4* H1v = (const uint4*)H1;
    int jr = lane >> 3, c8 = lane & 7;     // instr j: 8 rows (jr) x 8 chunks (c8)
    if (tid < 128) { ssum[tid] = 0.f; ssq[tid] = 0.f; }
    __syncthreads();
    f32x16 z;
#pragma unroll
    for (int r = 0; r < 16; r++) z[r] = 0.f;
    f32x16 acc[2][2] = {{z, z}, {z, z}};

    int trb = rbase + jr;
    int ivn[8];
#pragma unroll
    for (int j = 0; j < 8; j++) {
        int tr = trb + j * 8; tr = tr < NV ? tr : NV - 1;
        ivn[j] = nbr[tr];
    }
    uint4 G[8];
#pragma unroll
    for (int j = 0; j < 8; j++) {
        long rowi = (long)(ivn[j] >= 0 ? ivn[j] : NV);
        G[j] = H1v[rowi * 8 + c8];
    }
#pragma unroll
    for (int j = 0; j < 8; j++) {
        int tr = trb + j * 8; tr = tr < NV ? tr : NV - 1;
        ivn[j] = nbr[NV + tr];
    }
    uint4 bv[8];
#pragma unroll
    for (int s = 0; s < 4; s++) {
        bv[2 * s]     = W1b[(s * 4 + nt0 + 0) * 64 + lane];
        bv[2 * s + 1] = W1b[(s * 4 + nt0 + 1) * 64 + lane];
    }

    for (int k = 0; k < 27; k++) {
#pragma unroll
        for (int j = 0; j < 8; j++) {
            int r = j * 8 + jr;
            smW[U1(r, c8)] = G[j];
        }
        if (k < 26) {
#pragma unroll
            for (int j = 0; j < 8; j++) {
                long rowi = (long)(ivn[j] >= 0 ? ivn[j] : NV);
                G[j] = H1v[rowi * 8 + c8];
            }
            if (k < 25) {
                const int* nb = nbr + (k + 2) * NV;
#pragma unroll
                for (int j = 0; j < 8; j++) {
                    int tr = trb + j * 8; tr = tr < NV ? tr : NV - 1;
                    ivn[j] = nb[tr];
                }
            }
        }
#pragma unroll
        for (int s = 0; s < 4; s++) {
            int c = 2 * s + h;
            int slot = ((m + c) & 7) | (m & 24);
            uint4 a0 = smW[s * 64 + h * 32 + slot];
            uint4 a1 = smW[(4 + s) * 64 + h * 32 + slot];
            acc[0][0] = MFMA32(bc8(a0), bc8(bv[2 * s]),     acc[0][0]);
            acc[0][1] = MFMA32(bc8(a0), bc8(bv[2 * s + 1]), acc[0][1]);
            acc[1][0] = MFMA32(bc8(a1), bc8(bv[2 * s]),     acc[1][0]);
            acc[1][1] = MFMA32(bc8(a1), bc8(bv[2 * s + 1]), acc[1][1]);
        }
        if (k < 26) {
            const uint4* gW = W1b + (k + 1) * 1024;
#pragma unroll
            for (int s = 0; s < 4; s++) {
                bv[2 * s]     = gW[(s * 4 + nt0 + 0) * 64 + lane];
                bv[2 * s + 1] = gW[(s * 4 + nt0 + 1) * 64 + lane];
            }
        }
    }
    // epilogue: +b1, time-embed affine, write bf16 h2, accumulate stats2
    int col = lane & 31;
#pragma unroll
    for (int jn = 0; jn < 2; jn++) {
        int f = (nt0 + jn) * 32 + col;
        float bias = b1[f];
        float s_l = 0.f, q_l = 0.f;
#pragma unroll
        for (int i = 0; i < 2; i++) {
            int rt = rt0 + i;
#pragma unroll
            for (int r = 0; r < 16; r++) {
                int row = rt * 32 + (r & 3) + 8 * (r >> 2) + 4 * h;
                int g = n0 + row;
                if (g < NV) {
                    float val = acc[i][jn][r] + bias;
                    int b = b_idx[g];
                    float sc = tp[b * 256 + f];
                    float sh = tp[b * 256 + 128 + f];
                    float h2v = (1.0f + sc) * val + sh;
                    H2[(long)g * 128 + f] = f2b(h2v);
                    s_l += h2v; q_l += h2v * h2v;
                }
            }
        }
        atomicAdd(&ssum[f], s_l);
        atomicAdd(&ssq[f], q_l);
    }
    __syncthreads();
    if (tid < 128) {
        atomicAdd(&stats2[tid], ssum[tid]);
        atomicAdd(&stats2[128 + tid], ssq[tid]);
    }
}

__global__ __launch_bounds__(256, 2) void k_conv2(const unsigned short* __restrict__ H3,
                                                  const int* __restrict__ nbr,
                                                  const uint4* __restrict__ W2b,
                                                  const float* __restrict__ b2,
                                                  const float* __restrict__ x,
                                                  const uint4* __restrict__ Widb,
                                                  const float* __restrict__ bid,
                                                  unsigned short* __restrict__ H4) {
    __shared__ uint4 smA[4096];   // 4 waves x 1024 units (16 KB/wave)
    int tid = threadIdx.x;
    int w = tid >> 6, lane = tid & 63, m = lane & 31, h = lane >> 5;
    int n0 = blockIdx.x * 128;
    int rt0 = (w >> 1) * 2, nt0 = (w & 1) * 2;
    int rbase = n0 + rt0 * 32;
    uint4* smW = &smA[w * 1024];
    const uint4* H3v = (const uint4*)H3;
    int jr = lane >> 4, c16 = lane & 15;   // instr j: 4 rows (jr) x 16 chunks (c16)
    f32x16 z;
#pragma unroll
    for (int r = 0; r < 16; r++) z[r] = 0.f;
    f32x16 acc[2][2] = {{z, z}, {z, z}};

    int trb = rbase + jr;
    int ivn[16];
#pragma unroll
    for (int j = 0; j < 16; j++) {
        int tr = trb + j * 4; tr = tr < NV ? tr : NV - 1;
        ivn[j] = nbr[tr];
    }
    uint4 G[16];
#pragma unroll
    for (int j = 0; j < 16; j++) {
        long rowi = (long)(ivn[j] >= 0 ? ivn[j] : NV);
        G[j] = H3v[rowi * 16 + c16];
    }
#pragma unroll
    for (int j = 0; j < 16; j++) {
        int tr = trb + j * 4; tr = tr < NV ? tr : NV - 1;
        ivn[j] = nbr[NV + tr];
    }
    uint4 bv[16];
#pragma unroll
    for (int s = 0; s < 8; s++) {
        bv[2 * s]     = W2b[(s * 4 + nt0 + 0) * 64 + lane];
        bv[2 * s + 1] = W2b[(s * 4 + nt0 + 1) * 64 + lane];
    }

    for (int k = 0; k < 27; k++) {
#pragma unroll
        for (int j = 0; j < 16; j++) {
            int r = j * 4 + jr;
            smW[U2(r, c16)] = G[j];
        }
        if (k < 26) {
#pragma unroll
            for (int j = 0; j < 16; j++) {
                long rowi = (long)(ivn[j] >= 0 ? ivn[j] : NV);
                G[j] = H3v[rowi * 16 + c16];
            }
            if (k < 25) {
                const int* nb = nbr + (k + 2) * NV;
#pragma unroll
                for (int j = 0; j < 16; j++) {
                    int tr = trb + j * 4; tr = tr < NV ? tr : NV - 1;
                    ivn[j] = nb[tr];
                }
            }
        }
#pragma unroll
        for (int s = 0; s < 8; s++) {
            int c = 2 * s + h;
            int slot = ((m + c) & 7) | (m & 24);
            uint4 a0 = smW[s * 64 + h * 32 + slot];
            uint4 a1 = smW[(8 + s) * 64 + h * 32 + slot];
            acc[0][0] = MFMA32(bc8(a0), bc8(bv[2 * s]),     acc[0][0]);
            acc[0][1] = MFMA32(bc8(a0), bc8(bv[2 * s + 1]), acc[0][1]);
            acc[1][0] = MFMA32(bc8(a1), bc8(bv[2 * s]),     acc[1][0]);
            acc[1][1] = MFMA32(bc8(a1), bc8(bv[2 * s + 1]), acc[1][1]);
        }
        if (k < 26) {
            const uint4* gW = W2b + (k + 1) * 2048;
#pragma unroll
            for (int s = 0; s < 8; s++) {
                bv[2 * s]     = gW[(s * 4 + nt0 + 0) * 64 + lane];
                bv[2 * s + 1] = gW[(s * 4 + nt0 + 1) * 64 + lane];
            }
        }
    }
    // idconv: x (fp32, CI=64) @ Wid, register-direct (once per block, minor)
    int row0 = rbase + m;
    int row1 = row0 + 32;
    {
        uint4 a0[4], a1[4];
#pragma unroll
        for (int s = 0; s < 4; s++) {
            union { unsigned short e[8]; uint4 v; } u0, u1;
            u0.v = make_uint4(0, 0, 0, 0);
            u1.v = make_uint4(0, 0, 0, 0);
            if (row0 < NV) {
                const float4* xr = (const float4*)(x + (long)row0 * 64);
                float4 f0 = xr[(s * 2 + h) * 2], f1 = xr[(s * 2 + h) * 2 + 1];
                u0.e[0] = f2b(f0.x); u0.e[1] = f2b(f0.y); u0.e[2] = f2b(f0.z); u0.e[3] = f2b(f0.w);
                u0.e[4] = f2b(f1.x); u0.e[5] = f2b(f1.y); u0.e[6] = f2b(f1.z); u0.e[7] = f2b(f1.w);
            }
            if (row1 < NV) {
                const float4* xr = (const float4*)(x + (long)row1 * 64);
                float4 f0 = xr[(s * 2 + h) * 2], f1 = xr[(s * 2 + h) * 2 + 1];
                u1.e[0] = f2b(f0.x); u1.e[1] = f2b(f0.y); u1.e[2] = f2b(f0.z); u1.e[3] = f2b(f0.w);
                u1.e[4] = f2b(f1.x); u1.e[5] = f2b(f1.y); u1.e[6] = f2b(f1.z); u1.e[7] = f2b(f1.w);
            }
            a0[s] = u0.v; a1[s] = u1.v;
        }
#pragma unroll
        for (int s = 0; s < 4; s++) {
            uint4 bv0 = Widb[(s * 4 + nt0 + 0) * 64 + lane];
            uint4 bv1 = Widb[(s * 4 + nt0 + 1) * 64 + lane];
            acc[0][0] = MFMA32(bc8(a0[s]), bc8(bv0), acc[0][0]);
            acc[0][1] = MFMA32(bc8(a0[s]), bc8(bv1), acc[0][1]);
            acc[1][0] = MFMA32(bc8(a1[s]), bc8(bv0), acc[1][0]);
            acc[1][1] = MFMA32(bc8(a1[s]), bc8(bv1), acc[1][1]);
        }
    }
    // epilogue: + b2 + bid, write bf16 h4
    int col = lane & 31;
#pragma unroll
    for (int jn = 0; jn < 2; jn++) {
        int f = (nt0 + jn) * 32 + col;
        float bias = b2[f] + bid[f];
#pragma unroll
        for (int i = 0; i < 2; i++) {
            int rt = rt0 + i;
#pragma unroll
            for (int r = 0; r < 16; r++) {
                int row = rt * 32 + (r & 3) + 8 * (r >> 2) + 4 * h;
                int g = n0 + row;
                if (g < NV) H4[(long)g * 128 + f] = f2b(acc[i][jn][r] + bias);
            }
        }
    }
}

__global__ __launch_bounds__(256, 2) void k_down(const unsigned short* __restrict__ H4,
                                                 const int* __restrict__ nbrd,
                                                 const uint4* __restrict__ Wdb,
                                                 float* __restrict__ out) {
    __shared__ uint4 smA[4096];
    int tid = threadIdx.x;
    int w = tid >> 6, lane = tid & 63, m = lane & 31, h = lane >> 5;
    int n0 = blockIdx.x * 128;
    int rt0 = (w >> 1) * 2, nt0 = (w & 1) * 2;
    int rbase = n0 + rt0 * 32;
    uint4* smW = &smA[w * 1024];
    const uint4* H4v = (const uint4*)H4;
    int jr = lane >> 4, c16 = lane & 15;
    f32x16 z;
#pragma unroll
    for (int r = 0; r < 16; r++) z[r] = 0.f;
    f32x16 acc[2][2] = {{z, z}, {z, z}};

    int trb = rbase + jr;
    int ivn[16];
#pragma unroll
    for (int j = 0; j < 16; j++) {
        int tr = trb + j * 4; tr = tr < NDN ? tr : NDN - 1;
        ivn[j] = nbrd[tr];
    }
    uint4 G[16];
#pragma unroll
    for (int j = 0; j < 16; j++) G[j] = H4v[(long)ivn[j] * 16 + c16];
#pragma unroll
    for (int j = 0; j < 16; j++) {
        int tr = trb + j * 4; tr = tr < NDN ? tr : NDN - 1;
        ivn[j] = nbrd[NDN + tr];
    }
    uint4 bv[16];
#pragma unroll
    for (int s = 0; s < 8; s++) {
        bv[2 * s]     = Wdb[(s * 4 + nt0 + 0) * 64 + lane];
        bv[2 * s + 1] = Wdb[(s * 4 + nt0 + 1) * 64 + lane];
    }

    for (int k = 0; k < 8; k++) {
#pragma unroll
        for (int j = 0; j < 16; j++) {
            int r = j * 4 + jr;
            smW[U2(r, c16)] = G[j];
        }
        if (k < 7) {
#pragma unroll
            for (int j = 0; j < 16; j++) G[j] = H4v[(long)ivn[j] * 16 + c16];
            if (k < 6) {
                const int* nb = nbrd + (k + 2) * NDN;
#pragma unroll
                for (int j = 0; j < 16; j++) {
                    int tr = trb + j * 4; tr = tr < NDN ? tr : NDN - 1;
                    ivn[j] = nb[tr];
                }
            }
        }
#pragma unroll
        for (int s = 0; s < 8; s++) {
            int c = 2 * s + h;
            int slot = ((m + c) & 7) | (m & 24);
            uint4 a0 = smW[s * 64 + h * 32 + slot];
            uint4 a1 = smW[(8 + s) * 64 + h * 32 + slot];
            acc[0][0] = MFMA32(bc8(a0), bc8(bv[2 * s]),     acc[0][0]);
            acc[0][1] = MFMA32(bc8(a0), bc8(bv[2 * s + 1]), acc[0][1]);
            acc[1][0] = MFMA32(bc8(a1), bc8(bv[2 * s]),     acc[1][0]);
            acc[1][1] = MFMA32(bc8(a1), bc8(bv[2 * s + 1]), acc[1][1]);
        }
        if (k < 7) {
            const uint4* gW = Wdb + (k + 1) * 2048;
#pragma unroll
            for (int s = 0; s < 8; s++) {
                bv[2 * s]     = gW[(s * 4 + nt0 + 0) * 64 + lane];
                bv[2 * s + 1] = gW[(s * 4 + nt0 + 1) * 64 + lane];
            }
        }
    }
    int col = lane & 31;
#pragma unroll
    for (int jn = 0; jn < 2; jn++) {
        int f = (nt0 + jn) * 32 + col;
#pragma unroll
        for (int i = 0; i < 2; i++) {
            int rt = rt0 + i;
#pragma unroll
            for (int r = 0; r < 16; r++) {
                int row = rt * 32 + (r & 3) + 8 * (r >> 2) + 4 * h;
                int g = n0 + row;
                if (g < NDN) out[(long)g * 128 + f] = acc[i][jn][r];
            }
        }
    }
}

// ---------------- launch ----------------

extern "C" void kernel_launch(void* const* d_in, const int* in_sizes, int n_in,
                              void* d_out, int out_size, void* d_ws, size_t ws_size,
                              hipStream_t stream) {
    const float* x   = (const float*)d_in[0];
    const float* t   = (const float*)d_in[1];
    const int* b_idx = (const int*)d_in[2];
    const int* nbr   = (const int*)d_in[3];
    const int* nbrd  = (const int*)d_in[4];
    const float* g1  = (const float*)d_in[5];
    const float* be1 = (const float*)d_in[6];
    const float* W1  = (const float*)d_in[7];
    const float* b1  = (const float*)d_in[8];
    const float* Wt  = (const float*)d_in[9];
    const float* bt  = (const float*)d_in[10];
    const float* g2  = (const float*)d_in[11];
    const float* be2 = (const float*)d_in[12];
    const float* W2  = (const float*)d_in[13];
    const float* b2  = (const float*)d_in[14];
    const float* Wid = (const float*)d_in[15];
    const float* bid = (const float*)d_in[16];
    const float* Wd  = (const float*)d_in[17];
    float* out = (float*)d_out;

    char* ws = (char*)d_ws;
    float* stats1 = (float*)(ws + OFF_STATS1);
    float* stats2 = (float*)(ws + OFF_STATS2);
    float* tp     = (float*)(ws + OFF_TP);
    uint4* W1b    = (uint4*)(ws + OFF_W1B);
    uint4* W2b    = (uint4*)(ws + OFF_W2B);
    uint4* Wdb    = (uint4*)(ws + OFF_WDB);
    uint4* Widb   = (uint4*)(ws + OFF_WIDB);
    unsigned short* H1 = (unsigned short*)(ws + OFF_H1);
    unsigned short* H2 = (unsigned short*)(ws + OFF_H2);
    unsigned short* H4 = (unsigned short*)(ws + OFF_H4);

    k_init<<<1, 512, 0, stream>>>((float*)ws,
                                  (unsigned int*)(H1 + (long)NV * 64),
                                  (unsigned int*)(H2 + (long)NV * 128));
    k_stats1<<<400, 256, 0, stream>>>(x, stats1);
    k_tp<<<16, 256, 0, stream>>>(t, Wt, bt, tp);
    k_swz<<<108, 256, 0, stream>>>(W1, W1b, 27, 4);
    k_swz<<<216, 256, 0, stream>>>(W2, W2b, 27, 8);
    k_swz<<<64, 256, 0, stream>>>(Wd, Wdb, 8, 8);
    k_swz<<<4, 256, 0, stream>>>(Wid, Widb, 1, 4);
    k_h1<<<12500, 256, 0, stream>>>(x, g1, be1, stats1, H1);
    k_conv1<<<(NV + 127) / 128, 256, 0, stream>>>(H1, nbr, W1b, b1, b_idx, tp, H2, stats2);
    k_h3<<<12500, 256, 0, stream>>>(H2, g2, be2, stats2);
    k_conv2<<<(NV + 127) / 128, 256, 0, stream>>>(H2, nbr, W2b, b2, x, Widb, bid, H4);
    k_down<<<(NDN + 127) / 128, 256, 0, stream>>>(H4, nbrd, Wdb, out);
}

// Round 7
// 991.953 us; speedup vs baseline: 2.3608x; 2.3608x over previous
//
#include <hip/hip_runtime.h>

#define NV 200000
#define NDN 25000
#define EPSV 1e-5f

typedef short bf16x8 __attribute__((ext_vector_type(8)));
typedef float f32x16 __attribute__((ext_vector_type(16)));

static __device__ __forceinline__ float silu_f(float v) { return v / (1.0f + __expf(-v)); }
static __device__ __forceinline__ unsigned short f2b(float f) {
    unsigned u = __float_as_uint(f);
    return (unsigned short)((u + 0x7FFFu + ((u >> 16) & 1u)) >> 16);
}
static __device__ __forceinline__ float b2f(unsigned short h) {
    return __uint_as_float(((unsigned)h) << 16);
}
static __device__ __forceinline__ bf16x8 bc8(uint4 v) { return __builtin_bit_cast(bf16x8, v); }
#define MFMA32(a, b, c) __builtin_amdgcn_mfma_f32_32x32x16_bf16(a, b, c, 0, 0, 0)

// workspace byte offsets
#define OFF_STATS1 0                               // 128 f32
#define OFF_STATS2 512                             // 256 f32
#define OFF_TP     4096                            // 16*256 f32
#define OFF_W1B    32768                           // bf16 swizzled 27*64*128
#define OFF_W2B    (OFF_W1B + 27 * 64 * 128 * 2)   // 27*128*128
#define OFF_WDB    (OFF_W2B + 27 * 128 * 128 * 2)  // 8*128*128
#define OFF_WIDB   (OFF_WDB + 8 * 128 * 128 * 2)   // 64*128
#define OFF_H1     (2u << 20)                      // bf16 (NV+1)*64  (row NV = zeros)
#define OFF_H2     (28u << 20)                     // bf16 (NV+1)*128 (row NV = zeros; h2 then h3 in place)
#define OFF_H4     (80u << 20)                     // bf16 NV*128

// ---------------- small kernels ----------------

__global__ void k_init(float* stats, unsigned int* h1z, unsigned int* h2z) {
    int i = threadIdx.x;
    if (i < 384) stats[i] = 0.0f;
    else if (i < 416) h1z[i - 384] = 0u;   // H1 row NV
    else if (i < 480) h2z[i - 416] = 0u;   // H2 row NV
}

__global__ __launch_bounds__(256) void k_stats1(const float* __restrict__ x,
                                                float* __restrict__ stats) {
    int c = threadIdx.x & 63;
    int r0 = blockIdx.x * 4 + (threadIdx.x >> 6);
    float s = 0.f, q = 0.f;
    for (int r = r0; r < NV; r += gridDim.x * 4) {
        float v = x[r * 64 + c];
        s += v; q += v * v;
    }
    __shared__ float rs[256], rq[256];
    rs[threadIdx.x] = s; rq[threadIdx.x] = q;
    __syncthreads();
    if (threadIdx.x < 64) {
        s = rs[threadIdx.x] + rs[threadIdx.x + 64] + rs[threadIdx.x + 128] + rs[threadIdx.x + 192];
        q = rq[threadIdx.x] + rq[threadIdx.x + 64] + rq[threadIdx.x + 128] + rq[threadIdx.x + 192];
        atomicAdd(&stats[c], s);
        atomicAdd(&stats[64 + c], q);
    }
}

__global__ __launch_bounds__(256) void k_tp(const float* __restrict__ t,
                                            const float* __restrict__ Wt,
                                            const float* __restrict__ bt,
                                            float* __restrict__ tp) {
    __shared__ float st[256];
    int b = blockIdx.x, o = threadIdx.x;
    st[o] = silu_f(t[b * 256 + o]);
    __syncthreads();
    float acc = bt[o];
    for (int e = 0; e < 256; e++) acc += st[e] * Wt[e * 256 + o];
    tp[b * 256 + o] = acc;
}

// weights fp32 [K][CI][128] -> bf16 fragment-order units
__global__ __launch_bounds__(256) void k_swz(const float* __restrict__ W, uint4* __restrict__ dst,
                                             int Kc, int S) {
    int t = blockIdx.x * 256 + threadIdx.x;
    int total = Kc * S * 4 * 64;
    if (t >= total) return;
    int L = t & 63;
    int u = t >> 6;
    int nt = u & 3; u >>= 2;
    int s = u % S;
    int kk = u / S;
    int CI = S * 16;
    int c0 = s * 16 + (L >> 5) * 8;
    int f = nt * 32 + (L & 31);
    union { unsigned short e[8]; uint4 v; } uu;
#pragma unroll
    for (int j = 0; j < 8; j++) uu.e[j] = f2b(W[(kk * CI + c0 + j) * 128 + f]);
    dst[t] = uu.v;
}

__global__ __launch_bounds__(256) void k_h1(const float* __restrict__ x,
                                            const float* __restrict__ g1,
                                            const float* __restrict__ be1,
                                            const float* __restrict__ stats,
                                            unsigned short* __restrict__ H1) {
    int i = blockIdx.x * 256 + threadIdx.x;   // < NV*16
    if (i >= NV * 16) return;
    int c4 = (i & 15) * 4;
    float4 v = ((const float4*)x)[i];
    float vv[4] = {v.x, v.y, v.z, v.w};
    ushort4 o;
    unsigned short os[4];
#pragma unroll
    for (int j = 0; j < 4; j++) {
        int c = c4 + j;
        float m = stats[c] * (1.0f / NV);
        float var = stats[64 + c] * (1.0f / NV) - m * m;
        float a = g1[c] * rsqrtf(var + EPSV);
        float b = be1[c] - m * a;
        os[j] = f2b(silu_f(vv[j] * a + b));
    }
    o.x = os[0]; o.y = os[1]; o.z = os[2]; o.w = os[3];
    ((ushort4*)H1)[i] = o;
}

__global__ __launch_bounds__(256) void k_h3(unsigned short* __restrict__ H,
                                            const float* __restrict__ g2,
                                            const float* __restrict__ be2,
                                            const float* __restrict__ stats2) {
    int i = blockIdx.x * 256 + threadIdx.x;   // < NV*16 (uint4 of 8 bf16)
    if (i >= NV * 16) return;
    union { uint4 v; unsigned short e[8]; } uu;
    uu.v = ((const uint4*)H)[i];
    int f0 = (i & 15) * 8;
#pragma unroll
    for (int j = 0; j < 8; j++) {
        int f = f0 + j;
        float m = stats2[f] * (1.0f / NV);
        float var = stats2[128 + f] * (1.0f / NV) - m * m;
        float a = g2[f] * rsqrtf(var + EPSV);
        float b = be2[f] - m * a;
        uu.e[j] = f2b(silu_f(b2f(uu.e[j]) * a + b));
    }
    ((uint4*)H)[i] = uu.v;
}

// ---------------- conv kernels ----------------
// Register-resident software pipeline. NO LDS staging, NO barriers, NO spills.
// Wave tile 32 rows x 64 cols: acc = 2 x f32x16 (32), A-gather double buffer
// GA/GB (64), B 16 units (64) -> ~165 regs.
// Per iter k: issue gathers(k+1) -> idx(k+2) -> MFMAs(k), each s followed by
// the B(k+1) loads for that s. All waits target loads issued >= 1 iter earlier;
// waiting on B(k)[s] never drains gathers(k+1/k+2) (B is older in issue order).
// Block = 4 waves: 2 row-groups x 2 col-groups (64 rows x 128 cols), gather
// dup-2 within the CU (L1-absorbed, compulsory HBM traffic unchanged).

__global__ __launch_bounds__(256, 4) void k_conv1(const unsigned short* __restrict__ H1,
                                                  const int* __restrict__ nbr,
                                                  const uint4* __restrict__ W1b,
                                                  const float* __restrict__ b1,
                                                  const int* __restrict__ b_idx,
                                                  const float* __restrict__ tp,
                                                  unsigned short* __restrict__ H2,
                                                  float* __restrict__ stats2) {
    __shared__ float ssum[128], ssq[128];
    int tid = threadIdx.x;
    int w = tid >> 6, lane = tid & 63, m = lane & 31, h = lane >> 5;
    int rbase = blockIdx.x * 64 + (w >> 1) * 32;
    int nt0 = (w & 1) * 2;
    int row = rbase + m;                 // 3125*64 == NV exactly: no guards
    const uint4* Hv = (const uint4*)H1;  // 8 uint4 per row
    if (tid < 128) { ssum[tid] = 0.f; ssq[tid] = 0.f; }
    __syncthreads();
    f32x16 z;
#pragma unroll
    for (int r = 0; r < 16; r++) z[r] = 0.f;
    f32x16 acc[2] = {z, z};

    // prologue
    int iv = nbr[row];
    long ro = (iv >= 0) ? (long)iv : (long)NV;
    uint4 GA[4], GB[4], Bv[8];
#pragma unroll
    for (int s = 0; s < 4; s++) GA[s] = Hv[ro * 8 + 2 * s + h];
    int ivn = nbr[NV + row];
#pragma unroll
    for (int s = 0; s < 4; s++) {
        Bv[2 * s]     = W1b[(s * 4 + nt0) * 64 + lane];
        Bv[2 * s + 1] = W1b[(s * 4 + nt0 + 1) * 64 + lane];
    }

#define BODY1(cur, nxt, kk)                                                      \
    do {                                                                         \
        if ((kk) < 26) {                                                         \
            long r1 = (ivn >= 0) ? (long)ivn : (long)NV;                         \
            _Pragma("unroll") for (int s = 0; s < 4; s++)                        \
                nxt[s] = Hv[r1 * 8 + 2 * s + h];                                 \
        }                                                                        \
        if ((kk) < 25) ivn = nbr[((kk) + 2) * NV + row];                         \
        const uint4* gW = W1b + ((kk) + 1) * 1024;                               \
        _Pragma("unroll") for (int s = 0; s < 4; s++) {                          \
            acc[0] = MFMA32(bc8(cur[s]), bc8(Bv[2 * s]), acc[0]);                \
            acc[1] = MFMA32(bc8(cur[s]), bc8(Bv[2 * s + 1]), acc[1]);            \
            if ((kk) < 26) {                                                     \
                Bv[2 * s]     = gW[(s * 4 + nt0) * 64 + lane];                   \
                Bv[2 * s + 1] = gW[(s * 4 + nt0 + 1) * 64 + lane];               \
            }                                                                    \
        }                                                                        \
    } while (0)

    for (int k = 0; k < 26; k += 2) { BODY1(GA, GB, k); BODY1(GB, GA, k + 1); }
    BODY1(GA, GB, 26);
#undef BODY1

    // epilogue: +b1, time-embed affine, write bf16 h2, accumulate stats2
#pragma unroll
    for (int jn = 0; jn < 2; jn++) {
        int f = (nt0 + jn) * 32 + m;
        float bias = b1[f];
        float s_l = 0.f, q_l = 0.f;
#pragma unroll
        for (int r = 0; r < 16; r++) {
            int g = rbase + (r & 3) + 8 * (r >> 2) + 4 * h;
            float val = acc[jn][r] + bias;
            int b = b_idx[g];
            float sc = tp[b * 256 + f];
            float sh = tp[b * 256 + 128 + f];
            float h2v = (1.0f + sc) * val + sh;
            H2[(long)g * 128 + f] = f2b(h2v);
            s_l += h2v; q_l += h2v * h2v;
        }
        atomicAdd(&ssum[f], s_l);
        atomicAdd(&ssq[f], q_l);
    }
    __syncthreads();
    if (tid < 128) {
        atomicAdd(&stats2[tid], ssum[tid]);
        atomicAdd(&stats2[128 + tid], ssq[tid]);
    }
}

__global__ __launch_bounds__(256, 2) void k_conv2(const unsigned short* __restrict__ H3,
                                                  const int* __restrict__ nbr,
                                                  const uint4* __restrict__ W2b,
                                                  const float* __restrict__ b2,
                                                  const float* __restrict__ x,
                                                  const uint4* __restrict__ Widb,
                                                  const float* __restrict__ bid,
                                                  unsigned short* __restrict__ H4) {
    int tid = threadIdx.x;
    int w = tid >> 6, lane = tid & 63, m = lane & 31, h = lane >> 5;
    int rbase = blockIdx.x * 64 + (w >> 1) * 32;
    int nt0 = (w & 1) * 2;
    int row = rbase + m;                  // no guards: 3125*64 == NV
    const uint4* Hv = (const uint4*)H3;   // 16 uint4 per row
    f32x16 z;
#pragma unroll
    for (int r = 0; r < 16; r++) z[r] = 0.f;
    f32x16 acc[2] = {z, z};

    // prologue
    int iv = nbr[row];
    long ro = (iv >= 0) ? (long)iv : (long)NV;
    uint4 GA[8], GB[8], Bv[16];
#pragma unroll
    for (int s = 0; s < 8; s++) GA[s] = Hv[ro * 16 + 2 * s + h];
    int ivn = nbr[NV + row];
#pragma unroll
    for (int s = 0; s < 8; s++) {
        Bv[2 * s]     = W2b[(s * 4 + nt0) * 64 + lane];
        Bv[2 * s + 1] = W2b[(s * 4 + nt0 + 1) * 64 + lane];
    }

#define BODY2(cur, nxt, kk)                                                      \
    do {                                                                         \
        if ((kk) < 26) {                                                         \
            long r1 = (ivn >= 0) ? (long)ivn : (long)NV;                         \
            _Pragma("unroll") for (int s = 0; s < 8; s++)                        \
                nxt[s] = Hv[r1 * 16 + 2 * s + h];                                \
        }                                                                        \
        if ((kk) < 25) ivn = nbr[((kk) + 2) * NV + row];                         \
        const uint4* gW = W2b + ((kk) + 1) * 2048;                               \
        _Pragma("unroll") for (int s = 0; s < 8; s++) {                          \
            acc[0] = MFMA32(bc8(cur[s]), bc8(Bv[2 * s]), acc[0]);                \
            acc[1] = MFMA32(bc8(cur[s]), bc8(Bv[2 * s + 1]), acc[1]);            \
            if ((kk) < 26) {                                                     \
                Bv[2 * s]     = gW[(s * 4 + nt0) * 64 + lane];                   \
                Bv[2 * s + 1] = gW[(s * 4 + nt0 + 1) * 64 + lane];               \
            }                                                                    \
        }                                                                        \
    } while (0)

    for (int k = 0; k < 26; k += 2) { BODY2(GA, GB, k); BODY2(GB, GA, k + 1); }
    BODY2(GA, GB, 26);
#undef BODY2

    // idconv: x (fp32, CI=64) @ Wid, once per wave
    {
        const float4* xr = (const float4*)(x + (long)row * 64);
#pragma unroll
        for (int s = 0; s < 4; s++) {
            union { unsigned short e[8]; uint4 v; } u0;
            float4 f0 = xr[s * 4 + h * 2], f1 = xr[s * 4 + h * 2 + 1];
            u0.e[0] = f2b(f0.x); u0.e[1] = f2b(f0.y); u0.e[2] = f2b(f0.z); u0.e[3] = f2b(f0.w);
            u0.e[4] = f2b(f1.x); u0.e[5] = f2b(f1.y); u0.e[6] = f2b(f1.z); u0.e[7] = f2b(f1.w);
            uint4 b0 = Widb[(s * 4 + nt0) * 64 + lane];
            uint4 b1v = Widb[(s * 4 + nt0 + 1) * 64 + lane];
            acc[0] = MFMA32(bc8(u0.v), bc8(b0), acc[0]);
            acc[1] = MFMA32(bc8(u0.v), bc8(b1v), acc[1]);
        }
    }
    // epilogue: + b2 + bid, write bf16 h4
#pragma unroll
    for (int jn = 0; jn < 2; jn++) {
        int f = (nt0 + jn) * 32 + m;
        float bias = b2[f] + bid[f];
#pragma unroll
        for (int r = 0; r < 16; r++) {
            int g = rbase + (r & 3) + 8 * (r >> 2) + 4 * h;
            H4[(long)g * 128 + f] = f2b(acc[jn][r] + bias);
        }
    }
}

__global__ __launch_bounds__(256, 2) void k_down(const unsigned short* __restrict__ H4,
                                                 const int* __restrict__ nbrd,
                                                 const uint4* __restrict__ Wdb,
                                                 float* __restrict__ out) {
    int tid = threadIdx.x;
    int w = tid >> 6, lane = tid & 63, m = lane & 31, h = lane >> 5;
    int rbase = blockIdx.x * 64 + (w >> 1) * 32;
    int nt0 = (w & 1) * 2;
    int row = rbase + m;
    int rowc = row < NDN ? row : NDN - 1;
    const uint4* Hv = (const uint4*)H4;
    f32x16 z;
#pragma unroll
    for (int r = 0; r < 16; r++) z[r] = 0.f;
    f32x16 acc[2] = {z, z};

    int iv = nbrd[rowc];
    uint4 GA[8], GB[8], Bv[16];
#pragma unroll
    for (int s = 0; s < 8; s++) GA[s] = Hv[(long)iv * 16 + 2 * s + h];
    int ivn = nbrd[NDN + rowc];
#pragma unroll
    for (int s = 0; s < 8; s++) {
        Bv[2 * s]     = Wdb[(s * 4 + nt0) * 64 + lane];
        Bv[2 * s + 1] = Wdb[(s * 4 + nt0 + 1) * 64 + lane];
    }

#define BODYD(cur, nxt, kk)                                                      \
    do {                                                                         \
        if ((kk) < 7) {                                                          \
            _Pragma("unroll") for (int s = 0; s < 8; s++)                        \
                nxt[s] = Hv[(long)ivn * 16 + 2 * s + h];                         \
        }                                                                        \
        if ((kk) < 6) ivn = nbrd[((kk) + 2) * NDN + rowc];                       \
        const uint4* gW = Wdb + ((kk) + 1) * 2048;                               \
        _Pragma("unroll") for (int s = 0; s < 8; s++) {                          \
            acc[0] = MFMA32(bc8(cur[s]), bc8(Bv[2 * s]), acc[0]);                \
            acc[1] = MFMA32(bc8(cur[s]), bc8(Bv[2 * s + 1]), acc[1]);            \
            if ((kk) < 7) {                                                      \
                Bv[2 * s]     = gW[(s * 4 + nt0) * 64 + lane];                   \
                Bv[2 * s + 1] = gW[(s * 4 + nt0 + 1) * 64 + lane];               \
            }                                                                    \
        }                                                                        \
    } while (0)

    for (int k = 0; k < 8; k += 2) { BODYD(GA, GB, k); BODYD(GB, GA, k + 1); }
#undef BODYD

#pragma unroll
    for (int jn = 0; jn < 2; jn++) {
        int f = (nt0 + jn) * 32 + m;
#pragma unroll
        for (int r = 0; r < 16; r++) {
            int g = rbase + (r & 3) + 8 * (r >> 2) + 4 * h;
            if (g < NDN) out[(long)g * 128 + f] = acc[jn][r];
        }
    }
}

// ---------------- launch ----------------

extern "C" void kernel_launch(void* const* d_in, const int* in_sizes, int n_in,
                              void* d_out, int out_size, void* d_ws, size_t ws_size,
                              hipStream_t stream) {
    const float* x   = (const float*)d_in[0];
    const float* t   = (const float*)d_in[1];
    const int* b_idx = (const int*)d_in[2];
    const int* nbr   = (const int*)d_in[3];
    const int* nbrd  = (const int*)d_in[4];
    const float* g1  = (const float*)d_in[5];
    const float* be1 = (const float*)d_in[6];
    const float* W1  = (const float*)d_in[7];
    const float* b1  = (const float*)d_in[8];
    const float* Wt  = (const float*)d_in[9];
    const float* bt  = (const float*)d_in[10];
    const float* g2  = (const float*)d_in[11];
    const float* be2 = (const float*)d_in[12];
    const float* W2  = (const float*)d_in[13];
    const float* b2  = (const float*)d_in[14];
    const float* Wid = (const float*)d_in[15];
    const float* bid = (const float*)d_in[16];
    const float* Wd  = (const float*)d_in[17];
    float* out = (float*)d_out;

    char* ws = (char*)d_ws;
    float* stats1 = (float*)(ws + OFF_STATS1);
    float* stats2 = (float*)(ws + OFF_STATS2);
    float* tp     = (float*)(ws + OFF_TP);
    uint4* W1b    = (uint4*)(ws + OFF_W1B);
    uint4* W2b    = (uint4*)(ws + OFF_W2B);
    uint4* Wdb    = (uint4*)(ws + OFF_WDB);
    uint4* Widb   = (uint4*)(ws + OFF_WIDB);
    unsigned short* H1 = (unsigned short*)(ws + OFF_H1);
    unsigned short* H2 = (unsigned short*)(ws + OFF_H2);
    unsigned short* H4 = (unsigned short*)(ws + OFF_H4);

    k_init<<<1, 512, 0, stream>>>((float*)ws,
                                  (unsigned int*)(H1 + (long)NV * 64),
                                  (unsigned int*)(H2 + (long)NV * 128));
    k_stats1<<<400, 256, 0, stream>>>(x, stats1);
    k_tp<<<16, 256, 0, stream>>>(t, Wt, bt, tp);
    k_swz<<<108, 256, 0, stream>>>(W1, W1b, 27, 4);
    k_swz<<<216, 256, 0, stream>>>(W2, W2b, 27, 8);
    k_swz<<<64, 256, 0, stream>>>(Wd, Wdb, 8, 8);
    k_swz<<<4, 256, 0, stream>>>(Wid, Widb, 1, 4);
    k_h1<<<12500, 256, 0, stream>>>(x, g1, be1, stats1, H1);
    k_conv1<<<3125, 256, 0, stream>>>(H1, nbr, W1b, b1, b_idx, tp, H2, stats2);
    k_h3<<<12500, 256, 0, stream>>>(H2, g2, be2, stats2);
    k_conv2<<<3125, 256, 0, stream>>>(H2, nbr, W2b, b2, x, Widb, bid, H4);
    k_down<<<391, 256, 0, stream>>>(H4, nbrd, Wdb, out);
}